// Round 3
// baseline (266.532 us; speedup 1.0000x reference)
//
#include <hip/hip_runtime.h>

typedef _Float16 half8  __attribute__((ext_vector_type(8)));
typedef _Float16 half4v __attribute__((ext_vector_type(4)));
typedef _Float16 half2v __attribute__((ext_vector_type(2)));
typedef float  float4v  __attribute__((ext_vector_type(4)));

#define BN 2048
#define BD 512
#define NK 64          // keys per tile
#define NT (BN / NK)   // 32 tiles
#define LDK 520        // Kl pitch (fp16): reads land on 4*(key+quad) bank pattern (spread)
#define LDV 72         // Vt pitch (fp16): 144 B rows, 16B-aligned, 36 dwords (==4 mod 32)
#define LDP 72         // P pitch (fp16)
#define L2E 1.44269504f

__global__ __launch_bounds__(512, 2)
void attn_kernel(const float* __restrict__ x, float* __restrict__ y)
{
    __shared__ __align__(16) _Float16 Kl[NK * LDK];   // 66,560 B [key][dim]
    __shared__ __align__(16) _Float16 Vt[BD * LDV];   // 73,728 B [dim][key] chunk-rotated
    __shared__ __align__(16) _Float16 Pl[64 * LDP];   //  9,216 B [row][key]
    __shared__ float Qn[64];
    __shared__ float Ls[4][64];

    const int t      = threadIdx.x;
    const int w      = t >> 6;
    const int lane   = t & 63;
    const int lane15 = lane & 15;
    const int quad   = lane >> 4;
    const int rg     = w & 1;    // row-group: 32 rows
    const int kg     = w >> 1;   // 0..3: QK keys [kg*16,+16); PV dims [kg*128,+128)

    const int b  = blockIdx.y;
    const int q0 = blockIdx.x * 64;
    const float* xb = x + (size_t)b * BN * BD;

    // ---- Q preload: 32 rows as 2 half-frags; fp32 row-norm^2 = softmax shift ----
    half8 qf[2][16];
    {
        #pragma unroll
        for (int h = 0; h < 2; ++h) {
            float qn = 0.0f;
            const float* qrow = xb + (size_t)(q0 + rg * 32 + h * 16 + lane15) * BD + quad * 8;
            #pragma unroll
            for (int ks = 0; ks < 16; ++ks) {
                float4v a = *(const float4v*)(qrow + ks * 32);
                float4v c = *(const float4v*)(qrow + ks * 32 + 4);
                half8 q;
                q[0] = (_Float16)a[0]; q[1] = (_Float16)a[1];
                q[2] = (_Float16)a[2]; q[3] = (_Float16)a[3];
                q[4] = (_Float16)c[0]; q[5] = (_Float16)c[1];
                q[6] = (_Float16)c[2]; q[7] = (_Float16)c[3];
                qf[h][ks] = q;
                qn += a[0]*a[0] + a[1]*a[1] + a[2]*a[2] + a[3]*a[3]
                    + c[0]*c[0] + c[1]*c[1] + c[2]*c[2] + c[3]*c[3];
            }
            qn += __shfl_xor(qn, 16);
            qn += __shfl_xor(qn, 32);
            if (kg == 0 && lane < 16) Qn[rg * 32 + h * 16 + lane15] = qn;
        }
    }
    __syncthreads();
    float m4[2][4];
    #pragma unroll
    for (int h = 0; h < 2; ++h)
        #pragma unroll
        for (int r = 0; r < 4; ++r)
            m4[h][r] = Qn[rg * 32 + h * 16 + quad * 4 + r];

    // ---- staging: chunk c = keys [c*32, c*32+32) of the 64-key tile ----
    const int kp = (t >> 4) & 15;  // key-pair within chunk
    const int sg = t >> 8;         // half-split of the dim range
    const int d4 = t & 15;

    float4v ga[4], gb[4];
    auto load_chunk = [&](int kt, int c) {
        const float* r0 = xb + (size_t)(kt * NK + c * 32 + 2 * kp) * BD;
        #pragma unroll
        for (int j = 0; j < 4; ++j) {
            const int d = 4 * d4 + 64 * (sg * 4 + j);
            ga[j] = *(const float4v*)(r0 + d);
            gb[j] = *(const float4v*)(r0 + BD + d);
        }
    };
    auto store_chunk = [&](int c) {
        const int k0 = c * 32 + 2 * kp;
        const int swz = d4 & 3;
        #pragma unroll
        for (int j = 0; j < 4; ++j) {
            const int d = 4 * d4 + 64 * (sg * 4 + j);
            half4v ha, hb;
            ha[0] = (_Float16)ga[j][0]; ha[1] = (_Float16)ga[j][1];
            ha[2] = (_Float16)ga[j][2]; ha[3] = (_Float16)ga[j][3];
            hb[0] = (_Float16)gb[j][0]; hb[1] = (_Float16)gb[j][1];
            hb[2] = (_Float16)gb[j][2]; hb[3] = (_Float16)gb[j][3];
            *(half4v*)(&Kl[k0 * LDK + d])       = ha;
            *(half4v*)(&Kl[(k0 + 1) * LDK + d]) = hb;
            const int col = 2 * ((kp + 4 * swz) & 15) + c * 32;  // rotated pair column
            #pragma unroll
            for (int i = 0; i < 4; ++i) {
                half2v p; p[0] = ha[i]; p[1] = hb[i];
                *(half2v*)(&Vt[(d + i) * LDV + col]) = p;
            }
        }
    };

    float4v accO[2][8];
    #pragma unroll
    for (int h = 0; h < 2; ++h)
        #pragma unroll
        for (int nt = 0; nt < 8; ++nt) accO[h][nt] = (float4v){0.f, 0.f, 0.f, 0.f};
    float l_r[2][4] = {{0.f,0.f,0.f,0.f},{0.f,0.f,0.f,0.f}};

    const int vsw = (lane15 >> 2) & 3;             // Vt read-side rotation
    load_chunk(0, 0);

    for (int kt = 0; kt < NT; ++kt) {
        __syncthreads();                 // b1: prior tile's LDS reads complete
        store_chunk(0);
        load_chunk(kt, 1);               // partial exposure (~L2 latency)
        store_chunk(1);
        __syncthreads();                 // b2: Kl/Vt visible
        if (kt + 1 < NT) load_chunk(kt + 1, 0);   // hidden under MFMAs

        // ---- QK^T: 32 rows x 16 keys, B-frag shared across the 2 row-halves ----
        float4v s0 = {0.f,0.f,0.f,0.f}, s1 = {0.f,0.f,0.f,0.f};
        {
            const _Float16* kr = &Kl[(kg * 16 + lane15) * LDK + quad * 8];
            #pragma unroll
            for (int ks = 0; ks < 16; ++ks) {
                half8 bk = *(const half8*)(kr + ks * 32);
                s0 = __builtin_amdgcn_mfma_f32_16x16x32_f16(qf[0][ks], bk, s0, 0, 0, 0);
                s1 = __builtin_amdgcn_mfma_f32_16x16x32_f16(qf[1][ks], bk, s1, 0, 0, 0);
            }
        }

        // ---- P = exp(s - ||q||^2), unnormalized; stage to LDS (C/D -> A layout) ----
        #pragma unroll
        for (int r = 0; r < 4; ++r) {
            float p0 = exp2f((s0[r] - m4[0][r]) * L2E);
            float p1 = exp2f((s1[r] - m4[1][r]) * L2E);
            l_r[0][r] += p0;
            l_r[1][r] += p1;
            Pl[(rg * 32 + quad * 4 + r) * LDP + kg * 16 + lane15]      = (_Float16)p0;
            Pl[(rg * 32 + 16 + quad * 4 + r) * LDP + kg * 16 + lane15] = (_Float16)p1;
        }
        __syncthreads();                 // b3: P visible across kg waves

        // ---- O += P*V: dims [kg*128,+128), V B-frag shared across row-halves ----
        #pragma unroll
        for (int ks = 0; ks < 2; ++ks) {
            half8 ap0 = *(const half8*)(&Pl[(rg * 32 + lane15) * LDP + ks * 32 + quad * 8]);
            half8 ap1 = *(const half8*)(&Pl[(rg * 32 + 16 + lane15) * LDP + ks * 32 + quad * 8]);
            #pragma unroll
            for (int nt = 0; nt < 8; ++nt) {
                const int dim = kg * 128 + nt * 16 + lane15;
                half8 bv = *(const half8*)(&Vt[dim * LDV + ks * 32 + 8 * ((quad + vsw) & 3)]);
                accO[0][nt] = __builtin_amdgcn_mfma_f32_16x16x32_f16(ap0, bv, accO[0][nt], 0, 0, 0);
                accO[1][nt] = __builtin_amdgcn_mfma_f32_16x16x32_f16(ap1, bv, accO[1][nt], 0, 0, 0);
            }
        }
    }

    // ---- softmax denominators: reduce over key-lanes, combine the 4 kg groups ----
    #pragma unroll
    for (int h = 0; h < 2; ++h)
        #pragma unroll
        for (int r = 0; r < 4; ++r) {
            float l = l_r[h][r];
            l += __shfl_xor(l, 1);
            l += __shfl_xor(l, 2);
            l += __shfl_xor(l, 4);
            l += __shfl_xor(l, 8);
            if (lane15 == 0) Ls[kg][rg * 32 + h * 16 + quad * 4 + r] = l;
        }
    __syncthreads();

    float* yb = y + (size_t)b * BN * BD + (size_t)q0 * BD;
    #pragma unroll
    for (int h = 0; h < 2; ++h) {
        #pragma unroll
        for (int r = 0; r < 4; ++r) {
            const int row = rg * 32 + h * 16 + quad * 4 + r;
            const float linv = 1.0f / (Ls[0][row] + Ls[1][row] + Ls[2][row] + Ls[3][row]);
            #pragma unroll
            for (int nt = 0; nt < 8; ++nt) {
                yb[(size_t)row * BD + kg * 128 + nt * 16 + lane15] = accO[h][nt][r] * linv;
            }
        }
    }
}

extern "C" void kernel_launch(void* const* d_in, const int* in_sizes, int n_in,
                              void* d_out, int out_size, void* d_ws, size_t ws_size,
                              hipStream_t stream) {
    const float* x = (const float*)d_in[0];
    float* yo = (float*)d_out;
    dim3 grid(BN / 64, 8, 1);   // 32 q-blocks x 8 batches = 256 WGs (1/CU, 8 waves)
    dim3 block(512, 1, 1);
    attn_kernel<<<grid, block, 0, stream>>>(x, yo);
}